// Round 3
// baseline (122.878 us; speedup 1.0000x reference)
//
#include <hip/hip_runtime.h>
#include <math.h>

#define NPTS  8192
#define BATCH 4

typedef __bf16 bf16x8 __attribute__((ext_vector_type(8)));
typedef float  f32x16 __attribute__((ext_vector_type(16)));

// Grid: 1024 blocks = b(4) x ng(16) x mg(16); 256 threads = 4 waves.
// Block: 512 template rows (4 n-tiles per wave) x 512 source points staged in
// LDS (16 m-tiles). 26KB LDS + <=128 VGPR -> 4 blocks/CU, all 1024 co-resident.
// One mfma_f32_32x32x16_bf16 per (n-tile, m-tile): K=16 limb/norm packing
// makes the MFMA output the squared distance d2 directly (verified round 2).
__global__ __launch_bounds__(256, 4) void chamfer_mfma_kernel(
    const float* __restrict__ tpl, const float* __restrict__ src,
    unsigned* __restrict__ minsT, unsigned* __restrict__ minsS)
{
    __shared__ uint4 gvec[512 * 3];    // 24 KB: 2x16B g-vec per point, 48B stride
    __shared__ unsigned sminL[512];    // 2 KB: block-local source-side mins (raw fp32 bits)

    const int bid  = blockIdx.x;
    const int mg   = bid & 15;
    const int ng   = (bid >> 4) & 15;
    const int b    = bid >> 8;
    const int t    = threadIdx.x;
    const int lane = t & 63;
    const int wave = t >> 6;
    const int khalf = lane >> 5;   // which K-half (k 0-7 or 8-15) this lane supplies
    const int lr   = lane & 31;    // row (A) / col (B) within 32-tile

    const float* tb = tpl + (size_t)b * NPTS * 3;
    const float* sb = src + (size_t)b * NPTS * 3;

    sminL[t]       = 0x7f7f7f7fu;  // ~3.39e38
    sminL[t + 256] = 0x7f7f7f7fu;

    // ---- stage 512 source g-vectors (B operand), 2 points per thread ----
    // khalf0 slots: [-2xh,-2xl,-2xh,-2xl | -2yh,-2yl,-2yh,-2yl]
    // khalf1 slots: [-2zh,-2zl,-2zh,-2zl |   1,   1,  nsh, nsl]
    {
        const float2* s2 = (const float2*)(sb + (size_t)mg * 512 * 3);
        float2 q0 = s2[t * 3 + 0], q1 = s2[t * 3 + 1], q2 = s2[t * 3 + 2];
        float px[2] = {q0.x, q1.y};
        float py[2] = {q0.y, q2.x};
        float pz[2] = {q1.x, q2.y};
#pragma unroll
        for (int j = 0; j < 2; ++j) {
            float x = px[j], y = py[j], z = pz[j];
            float ns = x * x + y * y + z * z;
            __bf16 xh = (__bf16)x, yh = (__bf16)y, zh = (__bf16)z;
            float xl = x - (float)xh, yl = y - (float)yh, zl = z - (float)zh;
            __bf16 nsh = (__bf16)ns; float nsl = ns - (float)nsh;
            __bf16 xh2 = (__bf16)(-2.0f * (float)xh), xl2 = (__bf16)(-2.0f * xl);
            __bf16 yh2 = (__bf16)(-2.0f * (float)yh), yl2 = (__bf16)(-2.0f * yl);
            __bf16 zh2 = (__bf16)(-2.0f * (float)zh), zl2 = (__bf16)(-2.0f * zl);
            bf16x8 g0, g1;
            g0[0] = xh2; g0[1] = xl2; g0[2] = xh2; g0[3] = xl2;
            g0[4] = yh2; g0[5] = yl2; g0[6] = yh2; g0[7] = yl2;
            g1[0] = zh2; g1[1] = zl2; g1[2] = zh2; g1[3] = zl2;
            g1[4] = (__bf16)1.0f; g1[5] = (__bf16)1.0f;
            g1[6] = nsh; g1[7] = (__bf16)nsl;
            int p = t * 2 + j;
            gvec[p * 3 + 0] = __builtin_bit_cast(uint4, g0);
            gvec[p * 3 + 1] = __builtin_bit_cast(uint4, g1);
        }
    }

    // ---- build A fragments (template side), 4 n-tiles per wave ----
    // khalf0 slots: [xh,xh,xl,xl | yh,yh,yl,yl]
    // khalf1 slots: [zh,zh,zl,zl | nqh,nql,1,1]
    bf16x8 afrag[4];
    const int rowbase = ng * 512 + wave * 128;
#pragma unroll
    for (int nt = 0; nt < 4; ++nt) {
        int row = rowbase + nt * 32 + lr;
        float x = tb[row * 3 + 0], y = tb[row * 3 + 1], z = tb[row * 3 + 2];
        float nq = x * x + y * y + z * z;
        __bf16 xh = (__bf16)x, yh = (__bf16)y, zh = (__bf16)z;
        float xl = x - (float)xh, yl = y - (float)yh, zl = z - (float)zh;
        __bf16 nqh = (__bf16)nq; float nql = nq - (float)nqh;
        bf16x8 f0, f1;
        f0[0] = xh; f0[1] = xh; f0[2] = (__bf16)xl; f0[3] = (__bf16)xl;
        f0[4] = yh; f0[5] = yh; f0[6] = (__bf16)yl; f0[7] = (__bf16)yl;
        f1[0] = zh; f1[1] = zh; f1[2] = (__bf16)zl; f1[3] = (__bf16)zl;
        f1[4] = nqh; f1[5] = (__bf16)nql; f1[6] = (__bf16)1.0f; f1[7] = (__bf16)1.0f;
        afrag[nt] = khalf ? f1 : f0;
    }

    __syncthreads();

    // ---- main loop over the block's 16 m-tiles ----
    float tmin[4][16];
#pragma unroll
    for (int nt = 0; nt < 4; ++nt)
#pragma unroll
        for (int r = 0; r < 16; ++r) tmin[nt][r] = 3.0e38f;

    f32x16 czero = {};

    uint4 bu = gvec[lr * 3 + khalf];
    for (int mt = 0; mt < 16; ++mt) {
        int nmt = (mt < 15) ? (mt + 1) : 15;
        uint4 bnx = gvec[(nmt * 32 + lr) * 3 + khalf];   // prefetch next B frag
        bf16x8 bv = __builtin_bit_cast(bf16x8, bu);
        float sloc = 3.0e38f;
#pragma unroll
        for (int nt = 0; nt < 4; ++nt) {
            f32x16 c = __builtin_amdgcn_mfma_f32_32x32x16_bf16(afrag[nt], bv, czero, 0, 0, 0);
            // source-side: in-lane min tree over this lane's 16 rows
            // (3-ary nests -> v_min3_f32)
            float a0 = fminf(fminf(c[0], c[1]), c[2]);
            float a1 = fminf(fminf(c[3], c[4]), c[5]);
            float a2 = fminf(fminf(c[6], c[7]), c[8]);
            float a3 = fminf(fminf(c[9], c[10]), c[11]);
            float a4 = fminf(fminf(c[12], c[13]), c[14]);
            float b0 = fminf(fminf(a0, a1), a2);
            float b1 = fminf(fminf(a3, a4), c[15]);
            sloc = fminf(sloc, fminf(b0, b1));
            // template-side: per-(row-residue, lane) running min
#pragma unroll
            for (int r = 0; r < 16; ++r) tmin[nt][r] = fminf(tmin[nt][r], c[r]);
        }
        // combine the two row-halves (lane <-> lane+32), clamp, flush to LDS
        sloc = fminf(sloc, __shfl_xor(sloc, 32));
        sloc = fmaxf(sloc, 0.0f);  // kill bf16-split cancellation negatives
        if (lane < 32) atomicMin(&sminL[mt * 32 + lr], __float_as_uint(sloc));
        bu = bnx;
    }

    // ---- template-side epilogue: butterfly over the 32 columns ----
#pragma unroll
    for (int nt = 0; nt < 4; ++nt)
#pragma unroll
        for (int r = 0; r < 16; ++r) {
            float v = tmin[nt][r];
            v = fminf(v, __shfl_xor(v, 1));
            v = fminf(v, __shfl_xor(v, 2));
            v = fminf(v, __shfl_xor(v, 4));
            v = fminf(v, __shfl_xor(v, 8));
            v = fminf(v, __shfl_xor(v, 16));
            tmin[nt][r] = v;
        }
    if (lr == 0) {   // lanes 0 and 32: one atomic per template row
        unsigned* mT = minsT + (size_t)b * NPTS;
#pragma unroll
        for (int nt = 0; nt < 4; ++nt)
#pragma unroll
            for (int r = 0; r < 16; ++r) {
                int row = rowbase + nt * 32 + (r & 3) + 8 * (r >> 2) + 4 * khalf;
                atomicMin(&mT[row], __float_as_uint(fmaxf(tmin[nt][r], 0.0f)));
            }
    }

    __syncthreads();

    // ---- source-side flush: block-combined LDS mins -> global ----
    unsigned* mS = minsS + (size_t)b * NPTS + (size_t)mg * 512;
    atomicMin(&mS[t], sminL[t]);
    atomicMin(&mS[t + 256], sminL[t + 256]);
}

// Pass 2: sqrt + deterministic per-block partial sums (values are raw fp32
// bits, all >= 0 thanks to pre-atomic clamping).
__global__ __launch_bounds__(256) void chamfer_reduce_kernel(
    const unsigned* __restrict__ mins, float* __restrict__ partials)
{
    int t = threadIdx.x;
    int base = (blockIdx.x * 256 + t) * 4;
    float s0 = 0.f, s1 = 0.f;
#pragma unroll
    for (int k = 0; k < 4; ++k) {
        int i = base + k;
        float v = sqrtf(__uint_as_float(mins[i]));
        if (i < BATCH * NPTS) s0 += v; else s1 += v;
    }
    for (int off = 32; off > 0; off >>= 1) {
        s0 += __shfl_down(s0, off);
        s1 += __shfl_down(s1, off);
    }
    __shared__ float ws0[4], ws1[4];
    int wave = t >> 6;
    if ((t & 63) == 0) { ws0[wave] = s0; ws1[wave] = s1; }
    __syncthreads();
    if (t == 0) {
        partials[blockIdx.x * 2 + 0] = ws0[0] + ws0[1] + ws0[2] + ws0[3];
        partials[blockIdx.x * 2 + 1] = ws1[0] + ws1[1] + ws1[2] + ws1[3];
    }
}

// Pass 3: deterministic final combine.
__global__ void chamfer_final_kernel(const float* __restrict__ partials,
                                     float* __restrict__ out)
{
    if (threadIdx.x == 0) {
        float s0 = 0.f, s1 = 0.f;
        for (int i = 0; i < 64; ++i) {
            s0 += partials[i * 2 + 0];
            s1 += partials[i * 2 + 1];
        }
        out[0] = 0.5f * (s0 + s1) / (float)(BATCH * NPTS);
    }
}

extern "C" void kernel_launch(void* const* d_in, const int* in_sizes, int n_in,
                              void* d_out, int out_size, void* d_ws, size_t ws_size,
                              hipStream_t stream) {
    const float* tpl = (const float*)d_in[0];  // [B, N, 3] fp32
    const float* src = (const float*)d_in[1];  // [B, M, 3] fp32

    unsigned* mins = (unsigned*)d_ws;          // [2][B][8192] raw fp32 bits
    float* partials = (float*)((char*)d_ws + (size_t)2 * BATCH * NPTS * sizeof(unsigned));

    // Init mins to 0x7f7f7f7f (~3.39e38) — larger than any clamped d2.
    hipMemsetAsync(mins, 0x7f, (size_t)2 * BATCH * NPTS * sizeof(unsigned), stream);

    chamfer_mfma_kernel<<<1024, 256, 0, stream>>>(tpl, src, mins, mins + BATCH * NPTS);
    chamfer_reduce_kernel<<<(2 * BATCH * NPTS) / (256 * 4), 256, 0, stream>>>(mins, partials);
    chamfer_final_kernel<<<1, 64, 0, stream>>>(partials, (float*)d_out);
}

// Round 4
// 43.630 us; speedup vs baseline: 2.8164x; 2.8164x over previous
//
#include <hip/hip_runtime.h>
#include <math.h>

#define NPTS  8192
#define BATCH 4

typedef __bf16 bf16x8 __attribute__((ext_vector_type(8)));
typedef float  f32x16 __attribute__((ext_vector_type(16)));

// Grid: 1024 blocks = b(4) x ng(16) x mg(16); 256 threads = 4 waves.
// Block: 512 template rows (4 n-tiles/wave, nt-OUTER loop) x 512 source points
// staged in LDS (16 m-tiles, mt-INNER loop). Live set per thread kept ~82
// unified regs so __launch_bounds__(256,4)'s 128-reg cap holds WITHOUT spill
// (round-3 failure: tmin[4][16] blew the unified VGPR+AGPR budget -> scratch).
// One mfma_f32_32x32x16_bf16 per (n-tile, m-tile): K=16 limb/norm packing
// makes the MFMA output the squared distance d2 directly (verified rounds 2-3).
__global__ __launch_bounds__(256, 4) void chamfer_mfma_kernel(
    const float* __restrict__ tpl, const float* __restrict__ src,
    unsigned* __restrict__ minsT, unsigned* __restrict__ minsS)
{
    __shared__ uint4 gvec[512 * 3];    // 24 KB: 2x16B g-vec per point, 48B stride
    __shared__ unsigned sminL[512];    // 2 KB: block-local source-side mins (fp32 bits)

    const int bid  = blockIdx.x;
    const int mg   = bid & 15;
    const int ng   = (bid >> 4) & 15;
    const int b    = bid >> 8;
    const int t    = threadIdx.x;
    const int lane = t & 63;
    const int wave = t >> 6;
    const int khalf = lane >> 5;   // which K-half (k 0-7 or 8-15) this lane supplies
    const int lr   = lane & 31;    // row (A) / col (B) within 32-tile

    const float* tb = tpl + (size_t)b * NPTS * 3;
    const float* sb = src + (size_t)b * NPTS * 3;

    sminL[t]       = 0x7f7f7f7fu;  // ~3.39e38
    sminL[t + 256] = 0x7f7f7f7fu;

    // ---- stage 512 source g-vectors (B operand), 2 points per thread ----
    // khalf0 slots: [-2xh,-2xl,-2xh,-2xl | -2yh,-2yl,-2yh,-2yl]
    // khalf1 slots: [-2zh,-2zl,-2zh,-2zl |   1,   1,  nsh, nsl]
    {
        const float2* s2 = (const float2*)(sb + (size_t)mg * 512 * 3);
        float2 q0 = s2[t * 3 + 0], q1 = s2[t * 3 + 1], q2 = s2[t * 3 + 2];
        float px[2] = {q0.x, q1.y};
        float py[2] = {q0.y, q2.x};
        float pz[2] = {q1.x, q2.y};
#pragma unroll
        for (int j = 0; j < 2; ++j) {
            float x = px[j], y = py[j], z = pz[j];
            float ns = x * x + y * y + z * z;
            __bf16 xh = (__bf16)x, yh = (__bf16)y, zh = (__bf16)z;
            float xl = x - (float)xh, yl = y - (float)yh, zl = z - (float)zh;
            __bf16 nsh = (__bf16)ns; float nsl = ns - (float)nsh;
            __bf16 xh2 = (__bf16)(-2.0f * (float)xh), xl2 = (__bf16)(-2.0f * xl);
            __bf16 yh2 = (__bf16)(-2.0f * (float)yh), yl2 = (__bf16)(-2.0f * yl);
            __bf16 zh2 = (__bf16)(-2.0f * (float)zh), zl2 = (__bf16)(-2.0f * zl);
            bf16x8 g0, g1;
            g0[0] = xh2; g0[1] = xl2; g0[2] = xh2; g0[3] = xl2;
            g0[4] = yh2; g0[5] = yl2; g0[6] = yh2; g0[7] = yl2;
            g1[0] = zh2; g1[1] = zl2; g1[2] = zh2; g1[3] = zl2;
            g1[4] = (__bf16)1.0f; g1[5] = (__bf16)1.0f;
            g1[6] = nsh; g1[7] = (__bf16)nsl;
            int p = t * 2 + j;
            gvec[p * 3 + 0] = __builtin_bit_cast(uint4, g0);
            gvec[p * 3 + 1] = __builtin_bit_cast(uint4, g1);
        }
    }

    // ---- build A fragments (template side), 4 n-tiles per wave ----
    // khalf0 slots: [xh,xh,xl,xl | yh,yh,yl,yl]
    // khalf1 slots: [zh,zh,zl,zl | nqh,nql,1,1]
    bf16x8 afrag[4];
    const int rowbase = ng * 512 + wave * 128;
#pragma unroll
    for (int nt = 0; nt < 4; ++nt) {
        int row = rowbase + nt * 32 + lr;
        float x = tb[row * 3 + 0], y = tb[row * 3 + 1], z = tb[row * 3 + 2];
        float nq = x * x + y * y + z * z;
        __bf16 xh = (__bf16)x, yh = (__bf16)y, zh = (__bf16)z;
        float xl = x - (float)xh, yl = y - (float)yh, zl = z - (float)zh;
        __bf16 nqh = (__bf16)nq; float nql = nq - (float)nqh;
        bf16x8 f0, f1;
        f0[0] = xh; f0[1] = xh; f0[2] = (__bf16)xl; f0[3] = (__bf16)xl;
        f0[4] = yh; f0[5] = yh; f0[6] = (__bf16)yl; f0[7] = (__bf16)yl;
        f1[0] = zh; f1[1] = zh; f1[2] = (__bf16)zl; f1[3] = (__bf16)zl;
        f1[4] = nqh; f1[5] = (__bf16)nql; f1[6] = (__bf16)1.0f; f1[7] = (__bf16)1.0f;
        afrag[nt] = khalf ? f1 : f0;
    }

    __syncthreads();

    f32x16 czero = {};
    unsigned* mT = minsT + (size_t)b * NPTS;

    // ---- main loops: nt OUTER (tmin[16] live only), mt INNER ----
#pragma unroll
    for (int nt = 0; nt < 4; ++nt) {
        float tmin[16];
#pragma unroll
        for (int r = 0; r < 16; ++r) tmin[r] = 3.0e38f;

#pragma unroll 2
        for (int mt = 0; mt < 16; ++mt) {
            bf16x8 bv = __builtin_bit_cast(bf16x8, gvec[(mt * 32 + lr) * 3 + khalf]);
            f32x16 c = __builtin_amdgcn_mfma_f32_32x32x16_bf16(afrag[nt], bv, czero, 0, 0, 0);
            // template-side: per-(row-residue, lane-column) running min
#pragma unroll
            for (int r = 0; r < 16; ++r) tmin[r] = fminf(tmin[r], c[r]);
            // source-side: in-lane min tree (3-ary nests -> v_min3_f32)
            float a0 = fminf(fminf(c[0], c[1]), c[2]);
            float a1 = fminf(fminf(c[3], c[4]), c[5]);
            float a2 = fminf(fminf(c[6], c[7]), c[8]);
            float a3 = fminf(fminf(c[9], c[10]), c[11]);
            float a4 = fminf(fminf(c[12], c[13]), c[14]);
            float b0 = fminf(fminf(a0, a1), a2);
            float b1 = fminf(fminf(a3, a4), c[15]);
            float s  = fminf(b0, b1);
            // combine row-halves (lane <-> lane+32), clamp, accumulate in LDS
            s = fminf(s, __shfl_xor(s, 32));
            s = fmaxf(s, 0.0f);
            if (lane < 32) atomicMin(&sminL[mt * 32 + lr], __float_as_uint(s));
        }

        // template-side epilogue for this nt: butterfly over the 32 columns
#pragma unroll
        for (int r = 0; r < 16; ++r) {
            float v = tmin[r];
            v = fminf(v, __shfl_xor(v, 1));
            v = fminf(v, __shfl_xor(v, 2));
            v = fminf(v, __shfl_xor(v, 4));
            v = fminf(v, __shfl_xor(v, 8));
            v = fminf(v, __shfl_xor(v, 16));
            tmin[r] = v;
        }
        if (lr == 0) {   // lanes 0 and 32: one atomic per template row
#pragma unroll
            for (int r = 0; r < 16; ++r) {
                int row = rowbase + nt * 32 + (r & 3) + 8 * (r >> 2) + 4 * khalf;
                atomicMin(&mT[row], __float_as_uint(fmaxf(tmin[r], 0.0f)));
            }
        }
    }

    __syncthreads();

    // ---- source-side flush: block-combined LDS mins -> global ----
    unsigned* mS = minsS + (size_t)b * NPTS + (size_t)mg * 512;
    atomicMin(&mS[t], sminL[t]);
    atomicMin(&mS[t + 256], sminL[t + 256]);
}

// Pass 2: sqrt + deterministic per-block partial sums (values are raw fp32
// bits, all >= 0 thanks to pre-atomic clamping).
__global__ __launch_bounds__(256) void chamfer_reduce_kernel(
    const unsigned* __restrict__ mins, float* __restrict__ partials)
{
    int t = threadIdx.x;
    int base = (blockIdx.x * 256 + t) * 4;
    float s0 = 0.f, s1 = 0.f;
#pragma unroll
    for (int k = 0; k < 4; ++k) {
        int i = base + k;
        float v = sqrtf(__uint_as_float(mins[i]));
        if (i < BATCH * NPTS) s0 += v; else s1 += v;
    }
    for (int off = 32; off > 0; off >>= 1) {
        s0 += __shfl_down(s0, off);
        s1 += __shfl_down(s1, off);
    }
    __shared__ float ws0[4], ws1[4];
    int wave = t >> 6;
    if ((t & 63) == 0) { ws0[wave] = s0; ws1[wave] = s1; }
    __syncthreads();
    if (t == 0) {
        partials[blockIdx.x * 2 + 0] = ws0[0] + ws0[1] + ws0[2] + ws0[3];
        partials[blockIdx.x * 2 + 1] = ws1[0] + ws1[1] + ws1[2] + ws1[3];
    }
}

// Pass 3: deterministic final combine.
__global__ void chamfer_final_kernel(const float* __restrict__ partials,
                                     float* __restrict__ out)
{
    if (threadIdx.x == 0) {
        float s0 = 0.f, s1 = 0.f;
        for (int i = 0; i < 64; ++i) {
            s0 += partials[i * 2 + 0];
            s1 += partials[i * 2 + 1];
        }
        out[0] = 0.5f * (s0 + s1) / (float)(BATCH * NPTS);
    }
}

extern "C" void kernel_launch(void* const* d_in, const int* in_sizes, int n_in,
                              void* d_out, int out_size, void* d_ws, size_t ws_size,
                              hipStream_t stream) {
    const float* tpl = (const float*)d_in[0];  // [B, N, 3] fp32
    const float* src = (const float*)d_in[1];  // [B, M, 3] fp32

    unsigned* mins = (unsigned*)d_ws;          // [2][B][8192] raw fp32 bits
    float* partials = (float*)((char*)d_ws + (size_t)2 * BATCH * NPTS * sizeof(unsigned));

    // Init mins to 0x7f7f7f7f (~3.39e38) — larger than any clamped d2.
    hipMemsetAsync(mins, 0x7f, (size_t)2 * BATCH * NPTS * sizeof(unsigned), stream);

    chamfer_mfma_kernel<<<1024, 256, 0, stream>>>(tpl, src, mins, mins + BATCH * NPTS);
    chamfer_reduce_kernel<<<(2 * BATCH * NPTS) / (256 * 4), 256, 0, stream>>>(mins, partials);
    chamfer_final_kernel<<<1, 64, 0, stream>>>(partials, (float*)d_out);
}

// Round 5
// 34.918 us; speedup vs baseline: 3.5190x; 1.2495x over previous
//
#include <hip/hip_runtime.h>
#include <math.h>

#define NPTS  8192
#define BATCH 4

typedef __bf16 bf16x8 __attribute__((ext_vector_type(8)));
typedef float  f32x16 __attribute__((ext_vector_type(16)));

// min-fold with a DPP-shifted copy of v (VALU only, no DS traffic).
// CTRL: 0xB1 quad_perm xor1, 0x4E quad_perm xor2, 0x124 row_ror:4,
// 0x128 row_ror:8, 0x142 row_bcast15. RMASK gates which 16-lane rows update.
template<int CTRL, int RMASK>
__device__ __forceinline__ float dpp_min(float v) {
    int x = __builtin_amdgcn_update_dpp(__float_as_int(v), __float_as_int(v),
                                        CTRL, RMASK, 0xF, false);
    return fminf(v, __int_as_float(x));
}

// in-lane min over the 16 MFMA output rows (min3-friendly tree, 8 ops)
__device__ __forceinline__ float min16(const f32x16& c) {
    float t0 = fminf(fminf(c[0], c[1]), c[2]);
    float t1 = fminf(fminf(c[3], c[4]), c[5]);
    float t2 = fminf(fminf(c[6], c[7]), c[8]);
    float t3 = fminf(fminf(c[9], c[10]), c[11]);
    float t4 = fminf(fminf(c[12], c[13]), c[14]);
    float u0 = fminf(fminf(t0, t1), c[15]);
    float u1 = fminf(t2, t3);
    return fminf(fminf(u0, u1), t4);
}

// Grid: 1024 blocks = b(4) x ng(16) x mg(16); 256 threads = 4 waves.
// Block: 512 template rows x 512 LDS-staged source points. No global atomics:
// each block writes partial mins to its own slots (tpart/spart), pass 2
// reduces the 16 chunk-slots per point. Column-min via DPP (no DS).
__global__ __launch_bounds__(256, 4) void chamfer_mfma_kernel(
    const float* __restrict__ tpl, const float* __restrict__ src,
    float* __restrict__ tpart, float* __restrict__ spart)
{
    __shared__ uint4 gvec[512 * 3];      // 24 KB: 2x16B g-vec per point, 48B stride
    __shared__ unsigned sminL[1024];     // 4 KB: [khalf][512] source-side mins (fp32 bits)

    const int bid  = blockIdx.x;
    const int mg   = bid & 15;
    const int ng   = (bid >> 4) & 15;
    const int b    = bid >> 8;
    const int t    = threadIdx.x;
    const int lane = t & 63;
    const int wave = t >> 6;
    const int khalf = lane >> 5;   // which K-half this lane supplies / row-set it owns
    const int lr   = lane & 31;    // row (A) / col (B) within 32-tile

    const float* tb = tpl + (size_t)b * NPTS * 3;
    const float* sb = src + (size_t)b * NPTS * 3;

    sminL[t]       = 0x7f7f7f7fu;
    sminL[t + 256] = 0x7f7f7f7fu;
    sminL[t + 512] = 0x7f7f7f7fu;
    sminL[t + 768] = 0x7f7f7f7fu;

    // ---- stage 512 source g-vectors (B operand), 2 points per thread ----
    // khalf0 slots: [-2xh,-2xl,-2xh,-2xl | -2yh,-2yl,-2yh,-2yl]
    // khalf1 slots: [-2zh,-2zl,-2zh,-2zl |   1,   1,  nsh, nsl]
    {
        const float2* s2 = (const float2*)(sb + (size_t)mg * 512 * 3);
        float2 q0 = s2[t * 3 + 0], q1 = s2[t * 3 + 1], q2 = s2[t * 3 + 2];
        float px[2] = {q0.x, q1.y};
        float py[2] = {q0.y, q2.x};
        float pz[2] = {q1.x, q2.y};
#pragma unroll
        for (int j = 0; j < 2; ++j) {
            float x = px[j], y = py[j], z = pz[j];
            float ns = x * x + y * y + z * z;
            __bf16 xh = (__bf16)x, yh = (__bf16)y, zh = (__bf16)z;
            float xl = x - (float)xh, yl = y - (float)yh, zl = z - (float)zh;
            __bf16 nsh = (__bf16)ns; float nsl = ns - (float)nsh;
            __bf16 xh2 = (__bf16)(-2.0f * (float)xh), xl2 = (__bf16)(-2.0f * xl);
            __bf16 yh2 = (__bf16)(-2.0f * (float)yh), yl2 = (__bf16)(-2.0f * yl);
            __bf16 zh2 = (__bf16)(-2.0f * (float)zh), zl2 = (__bf16)(-2.0f * zl);
            bf16x8 g0, g1;
            g0[0] = xh2; g0[1] = xl2; g0[2] = xh2; g0[3] = xl2;
            g0[4] = yh2; g0[5] = yl2; g0[6] = yh2; g0[7] = yl2;
            g1[0] = zh2; g1[1] = zl2; g1[2] = zh2; g1[3] = zl2;
            g1[4] = (__bf16)1.0f; g1[5] = (__bf16)1.0f;
            g1[6] = nsh; g1[7] = (__bf16)nsl;
            int p = t * 2 + j;
            gvec[p * 3 + 0] = __builtin_bit_cast(uint4, g0);
            gvec[p * 3 + 1] = __builtin_bit_cast(uint4, g1);
        }
    }

    // ---- build A fragments (template side), 4 n-tiles per wave ----
    bf16x8 afrag[4];
    const int rowbase = ng * 512 + wave * 128;
#pragma unroll
    for (int nt = 0; nt < 4; ++nt) {
        int row = rowbase + nt * 32 + lr;
        float x = tb[row * 3 + 0], y = tb[row * 3 + 1], z = tb[row * 3 + 2];
        float nq = x * x + y * y + z * z;
        __bf16 xh = (__bf16)x, yh = (__bf16)y, zh = (__bf16)z;
        float xl = x - (float)xh, yl = y - (float)yh, zl = z - (float)zh;
        __bf16 nqh = (__bf16)nq; float nql = nq - (float)nqh;
        bf16x8 f0, f1;
        f0[0] = xh; f0[1] = xh; f0[2] = (__bf16)xl; f0[3] = (__bf16)xl;
        f0[4] = yh; f0[5] = yh; f0[6] = (__bf16)yl; f0[7] = (__bf16)yl;
        f1[0] = zh; f1[1] = zh; f1[2] = (__bf16)zl; f1[3] = (__bf16)zl;
        f1[4] = nqh; f1[5] = (__bf16)nql; f1[6] = (__bf16)1.0f; f1[7] = (__bf16)1.0f;
        afrag[nt] = khalf ? f1 : f0;
    }

    __syncthreads();

    f32x16 czero = {};
    const uint4* gv = gvec + lr * 3 + khalf;   // per-mt stride: 96 uint4 (1536 B)

#pragma unroll
    for (int nt = 0; nt < 4; ++nt) {
        float tmin[16];
#pragma unroll
        for (int r = 0; r < 16; ++r) tmin[r] = 3.0e38f;

#pragma unroll
        for (int mt2 = 0; mt2 < 8; ++mt2) {
            bf16x8 bv0 = __builtin_bit_cast(bf16x8, gv[(2 * mt2) * 96]);
            bf16x8 bv1 = __builtin_bit_cast(bf16x8, gv[(2 * mt2 + 1) * 96]);
            f32x16 c0 = __builtin_amdgcn_mfma_f32_32x32x16_bf16(afrag[nt], bv0, czero, 0, 0, 0);
            f32x16 c1 = __builtin_amdgcn_mfma_f32_32x32x16_bf16(afrag[nt], bv1, czero, 0, 0, 0);
            // template-side: paired fold -> v_min3_f32 (8 insts/MFMA)
#pragma unroll
            for (int r = 0; r < 16; ++r)
                tmin[r] = fminf(fminf(tmin[r], c0[r]), c1[r]);
            // source-side: in-lane tree per m-tile, per-khalf LDS slot (no shfl)
            float s0 = fmaxf(min16(c0), 0.0f);
            float s1 = fmaxf(min16(c1), 0.0f);
            atomicMin(&sminL[khalf * 512 + (2 * mt2) * 32 + lr], __float_as_uint(s0));
            atomicMin(&sminL[khalf * 512 + (2 * mt2 + 1) * 32 + lr], __float_as_uint(s1));
        }

        // ---- template-side column-min via DPP (VALU only) ----
        // quad xor1, xor2 -> quad min; row_ror 4,8 -> 16-lane row min (all lanes);
        // row_bcast15 (rows 1,3 only) -> lanes 31/63 hold min over their 32 cols.
#pragma unroll
        for (int r = 0; r < 16; ++r) {
            float v = tmin[r];
            v = dpp_min<0xB1, 0xF>(v);
            v = dpp_min<0x4E, 0xF>(v);
            v = dpp_min<0x124, 0xF>(v);
            v = dpp_min<0x128, 0xF>(v);
            v = dpp_min<0x142, 0xA>(v);
            tmin[r] = v;
        }
        if (lr == 31) {   // lanes 31 and 63
            float* tp = tpart + (((size_t)(b * 16 + ng)) * 512) * 16 + mg;
#pragma unroll
            for (int r = 0; r < 16; ++r) {
                int row_local = wave * 128 + nt * 32 + (r & 3) + 8 * (r >> 2) + 4 * khalf;
                tp[(size_t)row_local * 16] = fmaxf(tmin[r], 0.0f);
            }
        }
    }

    __syncthreads();

    // ---- source-side flush: fold khalf halves, write block's own slots ----
    {
        float v0 = fminf(__uint_as_float(sminL[t]),
                         __uint_as_float(sminL[512 + t]));
        float v1 = fminf(__uint_as_float(sminL[t + 256]),
                         __uint_as_float(sminL[768 + t]));
        float* sp = spart + (((size_t)(b * 16 + mg)) * 512) * 16 + ng;
        sp[(size_t)t * 16]         = v0;
        sp[(size_t)(t + 256) * 16] = v1;
    }
}

// Pass 2: per point, min over its 16 chunk-slots (contiguous float4 reads),
// sqrt, deterministic per-block partial sums. Blocks 0-127: template points,
// 128-255: source points (block-uniform).
__global__ __launch_bounds__(256) void chamfer_reduce_kernel(
    const float* __restrict__ part, float* __restrict__ partials)
{
    int t = threadIdx.x;
    size_t p = (size_t)blockIdx.x * 256 + t;
    const float4* v4 = (const float4*)(part + p * 16);
    float4 a = v4[0], bq = v4[1], cq = v4[2], dq = v4[3];
    float t0 = fminf(fminf(a.x, a.y), a.z);
    float t1 = fminf(fminf(a.w, bq.x), bq.y);
    float t2 = fminf(fminf(bq.z, bq.w), cq.x);
    float t3 = fminf(fminf(cq.y, cq.z), cq.w);
    float t4 = fminf(fminf(dq.x, dq.y), dq.z);
    float u0 = fminf(fminf(t0, t1), dq.w);
    float u1 = fminf(t2, t3);
    float v = sqrtf(fminf(fminf(u0, u1), t4));

    for (int off = 32; off > 0; off >>= 1) v += __shfl_down(v, off);
    __shared__ float ws[4];
    int wave = t >> 6;
    if ((t & 63) == 0) ws[wave] = v;
    __syncthreads();
    if (t == 0) partials[blockIdx.x] = ws[0] + ws[1] + ws[2] + ws[3];
}

// Pass 3: deterministic final combine (parallel load, fixed-slot sums).
__global__ void chamfer_final_kernel(const float* __restrict__ partials,
                                     float* __restrict__ out)
{
    int t = threadIdx.x;                 // 256 threads
    float v = partials[t];
    for (int off = 32; off > 0; off >>= 1) v += __shfl_down(v, off);
    __shared__ float ws[4];
    int wave = t >> 6;
    if ((t & 63) == 0) ws[wave] = v;
    __syncthreads();
    if (t == 0) {
        float s0 = ws[0] + ws[1];   // blocks 0-127   = template side
        float s1 = ws[2] + ws[3];   // blocks 128-255 = source side
        out[0] = 0.5f * (s0 + s1) / (float)(BATCH * NPTS);
    }
}

extern "C" void kernel_launch(void* const* d_in, const int* in_sizes, int n_in,
                              void* d_out, int out_size, void* d_ws, size_t ws_size,
                              hipStream_t stream) {
    const float* tpl = (const float*)d_in[0];  // [B, N, 3] fp32
    const float* src = (const float*)d_in[1];  // [B, M, 3] fp32

    // part: [65536][16] floats = 4 MB. First 32768 points: template (tpart),
    // next 32768: source (spart). Every slot is written each call -> no init.
    float* part     = (float*)d_ws;
    float* tpart    = part;
    float* spart    = part + (size_t)32768 * 16;
    float* partials = part + (size_t)65536 * 16;   // 256 floats

    chamfer_mfma_kernel<<<1024, 256, 0, stream>>>(tpl, src, tpart, spart);
    chamfer_reduce_kernel<<<256, 256, 0, stream>>>(part, partials);
    chamfer_final_kernel<<<1, 256, 0, stream>>>(partials, (float*)d_out);
}